// Round 2
// baseline (10294.305 us; speedup 1.0000x reference)
//
#include <hip/hip_runtime.h>
#include <math.h>

// Dims
constexpr int BB  = 128;
constexpr int TT  = 512;
constexpr int DIN = 88;
constexpr int DZ  = 80;
constexpr int DH  = 400;
constexpr int DE  = 100;
constexpr int DTR = 200;
constexpr int DOUT = DIN + DZ + DZ; // 248

// RNN W_hh partition (100 float4 k-chunks per row):
//   rows (tid<400):   chunks 0..47 in regs (192 VGPR)
//   helpers (tid>=400, j=tid-400<112): chunks 48..95 of row j in regs
//   rows<112:  chunks 96..99 streamed from L2 (4 cols x 112 rows)
//   rows>=112: chunks 48..73 from LDS (26 cols x 288 rows = 117 KB),
//              chunks 74..99 streamed from L2 (26 cols x 288 rows)
constexpr int NREG   = 48;
constexpr int HELPC0 = 48;
constexpr int RL0    = 112;   // first row using LDS/stream path
constexpr int NLROWS = DH - RL0; // 288
constexpr int NLDSC  = 26;    // LDS cols: chunks 48..73
constexpr int STRC0  = 74;    // stream cols for rows>=112: 74..99
constexpr int NSTRC  = 26;

__device__ __forceinline__ float dot4(float4 w, float4 h, float acc) {
    return fmaf(w.x, h.x, fmaf(w.y, h.y, fmaf(w.z, h.z, fmaf(w.w, h.w, acc))));
}
__device__ __forceinline__ float softplusf(float x) {
    return fmaxf(x, 0.f) + log1pf(__expf(-fabsf(x)));
}
__device__ __forceinline__ float sigmoidf(float x) {
    return 1.f / (1.f + __expf(-x));
}

// Pack W_hh (H,H) row-major into chunked layout: Wpk[kk*400 + j] = W_hh[j][4kk..4kk+3]
__global__ void pack_kernel(const float* __restrict__ W_hh, float4* __restrict__ Wpk) {
    int idx = blockIdx.x * 256 + threadIdx.x;
    if (idx < 100 * DH) {
        int kk = idx / DH, j = idx % DH;
        const float* s = W_hh + j * DH + 4 * kk;
        Wpk[idx] = make_float4(s[0], s[1], s[2], s[3]);
    }
}

// pre[b][tt][h] = sum_k x[b][T-1-tt][k]*W_ih[h][k] + b_ih[h] + b_hh[h]
__global__ __launch_bounds__(256) void pre_kernel(
    const float* __restrict__ x, const float* __restrict__ W_ih,
    const float* __restrict__ b_ih, const float* __restrict__ b_hh,
    float* __restrict__ pre) {
    int b = blockIdx.y;
    int tt0 = blockIdx.x * 8;
    __shared__ float xs[8][DIN];
    int tid = threadIdx.x;
    for (int idx = tid; idx < 8 * DIN; idx += 256) {
        int r = idx / DIN, k = idx % DIN;
        int tsrc = TT - 1 - (tt0 + r);
        xs[r][k] = x[(b * TT + tsrc) * DIN + k];
    }
    __syncthreads();
    for (int h = tid; h < DH; h += 256) {
        float bias = b_ih[h] + b_hh[h];
        float acc[8];
        #pragma unroll
        for (int r = 0; r < 8; ++r) acc[r] = bias;
        #pragma unroll
        for (int kk = 0; kk < DIN / 4; ++kk) {
            float4 w = *(const float4*)(W_ih + h * DIN + 4 * kk);
            #pragma unroll
            for (int r = 0; r < 8; ++r) {
                float4 xv = *(const float4*)(&xs[r][4 * kk]);
                acc[r] = dot4(w, xv, acc[r]);
            }
        }
        for (int r = 0; r < 8; ++r)
            pre[(size_t)(b * TT + tt0 + r) * DH + h] = acc[r];
    }
}

// Serial scan: h_t = relu(pre_t + W_hh h_{t-1}); writes h_t in-place over pre_t.
// One block per batch row; 512 threads (400 row-threads + 112 k-split helpers).
__global__ __launch_bounds__(512) void rnn_kernel(
    const float4* __restrict__ Wpk, const float* __restrict__ h0,
    float* __restrict__ hs) {
    extern __shared__ float smem[];
    float4* Wl    = (float4*)smem;                 // [NLDSC][288]
    float* hcur   = smem + NLDSC * NLROWS * 4;     // 400 floats (16B aligned)
    float* partial = hcur + DH;                    // 112 floats

    const int b = blockIdx.x, tid = threadIdx.x;
    const bool isRow = (tid < DH);
    const int row = isRow ? tid : tid - DH;  // helpers assist row j = tid-400
    const int c0  = isRow ? 0 : HELPC0;

    // Register-resident W chunks (48 per thread, 192 VGPR)
    float4 W[NREG];
    #pragma unroll
    for (int c = 0; c < NREG; ++c) W[c] = Wpk[(c0 + c) * DH + row];

    // LDS-resident W: chunks 48..73 for rows 112..399
    for (int i = tid; i < NLDSC * NLROWS; i += 512) {
        int c = i / NLROWS, r = i % NLROWS;
        Wl[i] = Wpk[(HELPC0 + c) * DH + (RL0 + r)];
    }
    if (isRow) hcur[row] = h0[row];
    __syncthreads();

    float* base = hs + (size_t)b * TT * DH;
    float pre_cur = isRow ? base[row] : 0.f;

    for (int tt = 0; tt < TT; ++tt) {
        float pre_nxt = 0.f;
        if (isRow && tt + 1 < TT) pre_nxt = base[(tt + 1) * DH + row];

        float a0 = 0.f, a1 = 0.f, a2 = 0.f, a3 = 0.f;
        // 48 register chunks (rows: k-chunks 0..47 | helpers: 48..95)
        #pragma unroll
        for (int c = 0; c < NREG; c += 4) {
            float4 h4;
            h4 = *(const float4*)(hcur + 4 * (c0 + c));     a0 = dot4(W[c],     h4, a0);
            h4 = *(const float4*)(hcur + 4 * (c0 + c + 1)); a1 = dot4(W[c + 1], h4, a1);
            h4 = *(const float4*)(hcur + 4 * (c0 + c + 2)); a2 = dot4(W[c + 2], h4, a2);
            h4 = *(const float4*)(hcur + 4 * (c0 + c + 3)); a3 = dot4(W[c + 3], h4, a3);
        }
        if (isRow) {
            if (row >= RL0) {
                #pragma unroll
                for (int c = 0; c < NLDSC; ++c) {
                    float4 w  = Wl[c * NLROWS + (row - RL0)];
                    float4 h4 = *(const float4*)(hcur + 4 * (HELPC0 + c));
                    if ((c & 3) == 0)      a0 = dot4(w, h4, a0);
                    else if ((c & 3) == 1) a1 = dot4(w, h4, a1);
                    else if ((c & 3) == 2) a2 = dot4(w, h4, a2);
                    else                   a3 = dot4(w, h4, a3);
                }
                #pragma unroll
                for (int c = 0; c < NSTRC; ++c) {
                    float4 w  = Wpk[(STRC0 + c) * DH + row];
                    float4 h4 = *(const float4*)(hcur + 4 * (STRC0 + c));
                    if ((c & 3) == 0)      a0 = dot4(w, h4, a0);
                    else if ((c & 3) == 1) a1 = dot4(w, h4, a1);
                    else if ((c & 3) == 2) a2 = dot4(w, h4, a2);
                    else                   a3 = dot4(w, h4, a3);
                }
            } else {
                #pragma unroll
                for (int c = 0; c < 4; ++c) {  // chunks 96..99
                    float4 w  = Wpk[(96 + c) * DH + row];
                    float4 h4 = *(const float4*)(hcur + 4 * (96 + c));
                    if (c == 0)      a0 = dot4(w, h4, a0);
                    else if (c == 1) a1 = dot4(w, h4, a1);
                    else if (c == 2) a2 = dot4(w, h4, a2);
                    else             a3 = dot4(w, h4, a3);
                }
            }
        } else {
            partial[row] = (a0 + a1) + (a2 + a3);
        }
        __syncthreads();  // barrier1: all hcur reads done; partial visible
        if (isRow) {
            float acc = pre_cur + (a0 + a1) + (a2 + a3);
            if (row < RL0) acc += partial[row];
            float v = fmaxf(acc, 0.f);
            hcur[row] = v;
            base[tt * DH + row] = v;
            pre_cur = pre_nxt;
        }
        __syncthreads();  // barrier2: hcur ready for next step
    }
}

// Fused downstream: per (b, 8-t chunk): z (incl. t-1 row), gate/prop/trans, emission.
// 320 threads so P1's 320 GEMV tasks (2 parts x 80 outs x 2 row-halves) map 1:1.
__global__ __launch_bounds__(320) void e_kernel(
    const float* __restrict__ hs, const float* __restrict__ eps,
    const float* __restrict__ z0,
    const float* __restrict__ W_loc, const float* __restrict__ b_loc,
    const float* __restrict__ W_scale, const float* __restrict__ b_scale,
    const float* __restrict__ gW1, const float* __restrict__ gb1,
    const float* __restrict__ gW2, const float* __restrict__ gb2,
    const float* __restrict__ pW1, const float* __restrict__ pb1,
    const float* __restrict__ pW2, const float* __restrict__ pb2,
    const float* __restrict__ sW, const float* __restrict__ sb,
    const float* __restrict__ lW, const float* __restrict__ lb,
    const float* __restrict__ eW1, const float* __restrict__ eb1,
    const float* __restrict__ eW2, const float* __restrict__ eb2,
    const float* __restrict__ eW3, const float* __restrict__ eb3,
    float* __restrict__ out) {
    __shared__ float hsr[9][DH];
    __shared__ float zst[2][9][DZ];
    __shared__ float zl[9][DZ];
    __shared__ float A[8][DTR];
    __shared__ float P[8][DTR];
    __shared__ float gate[8][DZ];
    __shared__ float prop[8][DZ];
    __shared__ float h1[8][DE];
    __shared__ float h2[8][DE];

    int b = blockIdx.y;
    int t0 = blockIdx.x * 8;
    int tid = threadIdx.x;
    int r0 = (t0 == 0) ? 1 : 0;

    // P0: stage rnn_out rows (hs index T-1-t)
    for (int idx = tid; idx < 9 * DH; idx += 320) {
        int r = idx / DH, k = idx % DH;
        int t = t0 - 1 + r;
        if (t >= 0) hsr[r][k] = hs[((size_t)b * TT + (TT - 1 - t)) * DH + k];
    }
    __syncthreads();

    // P1: z_loc / z_scale pre-activations. 320 tasks: (rh, part, o)
    {
        int rh = tid / 160, rem = tid % 160;
        int part = rem / 80, o = rem % 80;
        int rbeg = rh ? 5 : r0;
        int rend = rh ? 9 : 5;
        const float* Wrow = (part ? W_scale : W_loc) + o * DH;
        float bias = part ? b_scale[o] : b_loc[o];
        for (int r = rbeg; r < rend; ++r) {
            float ac0 = bias, ac1 = 0.f;
            #pragma unroll
            for (int kk = 0; kk < DH / 4; kk += 2) {
                float4 w0 = *(const float4*)(Wrow + 4 * kk);
                float4 h0v = *(const float4*)(&hsr[r][4 * kk]);
                ac0 = dot4(w0, h0v, ac0);
                float4 w1 = *(const float4*)(Wrow + 4 * kk + 4);
                float4 h1v = *(const float4*)(&hsr[r][4 * kk + 4]);
                ac1 = dot4(w1, h1v, ac1);
            }
            zst[part][r][o] = ac0 + ac1;
        }
    }
    __syncthreads();

    // P1b: z = z_loc + softplus(z_scale_pre) * eps   (row -1 -> z0)
    for (int idx = tid; idx < 9 * DZ; idx += 320) {
        int r = idx / DZ, o = idx % DZ;
        int t = t0 - 1 + r;
        float zv;
        if (t < 0) zv = z0[o];
        else {
            float sp = softplusf(zst[1][r][o]);
            zv = zst[0][r][o] + sp * eps[((size_t)b * TT + t) * DZ + o];
        }
        zl[r][o] = zv;
    }
    __syncthreads();

    // P2: A = relu(zs@gW1^T+gb1), P = relu(zs@pW1^T+pb1); 400 tasks (rh, o)
    for (int idx = tid; idx < 400; idx += 320) {
        int rh = idx / 200, o = idx % 200;
        const float* g = gW1 + o * DZ;
        const float* p = pW1 + o * DZ;
        float bg = gb1[o], bp = pb1[o];
        for (int r = rh * 4; r < rh * 4 + 4; ++r) {
            float ag = bg, ap = bp;
            #pragma unroll
            for (int kk = 0; kk < DZ / 4; ++kk) {
                float4 zv = *(const float4*)(&zl[r][4 * kk]);
                float4 wg = *(const float4*)(g + 4 * kk);
                float4 wp = *(const float4*)(p + 4 * kk);
                ag = dot4(wg, zv, ag);
                ap = dot4(wp, zv, ap);
            }
            A[r][o] = fmaxf(ag, 0.f);
            P[r][o] = fmaxf(ap, 0.f);
        }
    }
    __syncthreads();

    // P3: gate = sigmoid(A@gW2^T+gb2), prop = P@pW2^T+pb2  (o-minor for W reuse)
    for (int idx = tid; idx < 8 * DZ; idx += 320) {
        int o = idx % DZ, r = idx / DZ;
        float ag = gb2[o], ap = pb2[o];
        const float* g = gW2 + o * DTR;
        const float* p = pW2 + o * DTR;
        #pragma unroll
        for (int kk = 0; kk < DTR / 4; ++kk) {
            float4 av = *(const float4*)(&A[r][4 * kk]);
            float4 pv = *(const float4*)(&P[r][4 * kk]);
            float4 wg = *(const float4*)(g + 4 * kk);
            float4 wp = *(const float4*)(p + 4 * kk);
            ag = dot4(wg, av, ag);
            ap = dot4(wp, pv, ap);
        }
        gate[r][o] = sigmoidf(ag);
        prop[r][o] = ap;
    }
    __syncthreads();

    // P4: trans_loc / trans_scale -> out[88..248)
    for (int idx = tid; idx < 8 * DZ; idx += 320) {
        int o = idx % DZ, r = idx / DZ;
        int t = t0 + r;
        float al = lb[o], as_ = sb[o];
        const float* lw = lW + o * DZ;
        const float* sw = sW + o * DZ;
        #pragma unroll
        for (int kk = 0; kk < DZ / 4; ++kk) {
            float4 zv = *(const float4*)(&zl[r][4 * kk]);
            float4 wl = *(const float4*)(lw + 4 * kk);
            al = dot4(wl, zv, al);
            float4 pv = *(const float4*)(&prop[r][4 * kk]);
            pv.x = fmaxf(pv.x, 0.f); pv.y = fmaxf(pv.y, 0.f);
            pv.z = fmaxf(pv.z, 0.f); pv.w = fmaxf(pv.w, 0.f);
            float4 ws_ = *(const float4*)(sw + 4 * kk);
            as_ = dot4(ws_, pv, as_);
        }
        float g = gate[r][o];
        float tl = (1.f - g) * al + g * prop[r][o];
        size_t ob = ((size_t)b * TT + t) * DOUT;
        out[ob + DIN + o]      = tl;
        out[ob + DIN + DZ + o] = softplusf(as_);
    }
    __syncthreads();

    // P5: h1 = relu(z@eW1^T+eb1); z for t=t0+r is zl[r+1]
    for (int idx = tid; idx < 8 * DE; idx += 320) {
        int o = idx % DE, r = idx / DE;
        float a = eb1[o];
        const float* w = eW1 + o * DZ;
        #pragma unroll
        for (int kk = 0; kk < DZ / 4; ++kk) {
            float4 zv = *(const float4*)(&zl[r + 1][4 * kk]);
            float4 wv = *(const float4*)(w + 4 * kk);
            a = dot4(wv, zv, a);
        }
        h1[r][o] = fmaxf(a, 0.f);
    }
    __syncthreads();

    // P6: h2 = relu(h1@eW2^T+eb2)
    for (int idx = tid; idx < 8 * DE; idx += 320) {
        int o = idx % DE, r = idx / DE;
        float a = eb2[o];
        const float* w = eW2 + o * DE;
        #pragma unroll
        for (int kk = 0; kk < DE / 4; ++kk) {
            float4 hv = *(const float4*)(&h1[r][4 * kk]);
            float4 wv = *(const float4*)(w + 4 * kk);
            a = dot4(wv, hv, a);
        }
        h2[r][o] = fmaxf(a, 0.f);
    }
    __syncthreads();

    // P7: emis = sigmoid(h2@eW3^T+eb3) -> out[0..88)
    for (int idx = tid; idx < 8 * DIN; idx += 320) {
        int o = idx % DIN, r = idx / DIN;
        float a = eb3[o];
        const float* w = eW3 + o * DE;
        #pragma unroll
        for (int kk = 0; kk < DE / 4; ++kk) {
            float4 hv = *(const float4*)(&h2[r][4 * kk]);
            float4 wv = *(const float4*)(w + 4 * kk);
            a = dot4(wv, hv, a);
        }
        out[((size_t)b * TT + t0 + r) * DOUT + o] = sigmoidf(a);
    }
}

extern "C" void kernel_launch(void* const* d_in, const int* in_sizes, int n_in,
                              void* d_out, int out_size, void* d_ws, size_t ws_size,
                              hipStream_t stream) {
    const float* x       = (const float*)d_in[0];
    const float* eps     = (const float*)d_in[1];
    const float* W_ih    = (const float*)d_in[2];
    const float* W_hh    = (const float*)d_in[3];
    const float* b_ih    = (const float*)d_in[4];
    const float* b_hh    = (const float*)d_in[5];
    const float* h0      = (const float*)d_in[6];
    const float* z0      = (const float*)d_in[7];
    const float* W_loc   = (const float*)d_in[8];
    const float* b_loc   = (const float*)d_in[9];
    const float* W_scale = (const float*)d_in[10];
    const float* b_scale = (const float*)d_in[11];
    const float* gW1 = (const float*)d_in[12];
    const float* gb1 = (const float*)d_in[13];
    const float* gW2 = (const float*)d_in[14];
    const float* gb2 = (const float*)d_in[15];
    const float* pW1 = (const float*)d_in[16];
    const float* pb1 = (const float*)d_in[17];
    const float* pW2 = (const float*)d_in[18];
    const float* pb2 = (const float*)d_in[19];
    const float* sW  = (const float*)d_in[20];
    const float* sb  = (const float*)d_in[21];
    const float* lW  = (const float*)d_in[22];
    const float* lb  = (const float*)d_in[23];
    const float* eW1 = (const float*)d_in[24];
    const float* eb1 = (const float*)d_in[25];
    const float* eW2 = (const float*)d_in[26];
    const float* eb2 = (const float*)d_in[27];
    const float* eW3 = (const float*)d_in[28];
    const float* eb3 = (const float*)d_in[29];

    float* wsf = (float*)d_ws;
    float* prebuf = wsf;                                 // B*T*H floats
    float4* Wpk = (float4*)(wsf + (size_t)BB * TT * DH); // 100*400 float4

    pack_kernel<<<(100 * DH + 255) / 256, 256, 0, stream>>>(W_hh, Wpk);
    pre_kernel<<<dim3(TT / 8, BB), 256, 0, stream>>>(x, W_ih, b_ih, b_hh, prebuf);

    size_t smem = (size_t)NLDSC * NLROWS * sizeof(float4)
                + DH * sizeof(float) + RL0 * sizeof(float);
    hipFuncSetAttribute((const void*)rnn_kernel,
                        hipFuncAttributeMaxDynamicSharedMemorySize, (int)smem);
    rnn_kernel<<<dim3(BB), dim3(512), smem, stream>>>(Wpk, h0, prebuf);

    e_kernel<<<dim3(TT / 8, BB), 320, 0, stream>>>(
        prebuf, eps, z0, W_loc, b_loc, W_scale, b_scale,
        gW1, gb1, gW2, gb2, pW1, pb1, pW2, pb2, sW, sb, lW, lb,
        eW1, eb1, eW2, eb2, eW3, eb3, (float*)d_out);
}

// Round 3
// 4629.646 us; speedup vs baseline: 2.2236x; 2.2236x over previous
//
#include <hip/hip_runtime.h>
#include <math.h>

// Dims
constexpr int BB  = 128;
constexpr int TT  = 512;
constexpr int DIN = 88;
constexpr int DZ  = 80;
constexpr int DH  = 400;
constexpr int DE  = 100;
constexpr int DTR = 200;
constexpr int DOUT = DIN + DZ + DZ; // 248
constexpr int TCH = 16;             // t-chunk for e_kernel / pre_kernel

// RNN W_hh partition (100 float4 k-chunks per row of W_hh):
//  row threads (tid<400):  chunks 0..47 in regs (192 VGPR, asm-pinned)
//  helpers (tid>=400):     chunks 48..95 of row tid-400 (<112) in regs (pinned)
//  rows <112:   chunks 96..99 streamed from L2
//  rows >=112:  chunks 48..77 in LDS (30 cols x 288 rows = 135 KB)
//               chunks 78..99 streamed from L2 (~99 KB region, L2-resident)
constexpr int NREG   = 48;
constexpr int HELPC0 = 48;
constexpr int RL0    = 112;
constexpr int NLROWS = DH - RL0;  // 288
constexpr int NLDSC  = 30;        // LDS cols: chunks 48..77
constexpr int STRC0  = 78;
constexpr int NSTRC  = 22;

__device__ __forceinline__ float dot4(float4 w, float4 h, float acc) {
    return fmaf(w.x, h.x, fmaf(w.y, h.y, fmaf(w.z, h.z, fmaf(w.w, h.w, acc))));
}
__device__ __forceinline__ float softplusf(float x) {
    return fmaxf(x, 0.f) + log1pf(__expf(-fabsf(x)));
}
__device__ __forceinline__ float sigmoidf(float x) {
    return 1.f / (1.f + __expf(-x));
}
#define PIN4(w) asm volatile("" : "+v"((w).x), "+v"((w).y), "+v"((w).z), "+v"((w).w))

// Generic transpose-pack: dst[kk*dstStride + dstOff + o] = float4(src[o*K+4kk..])
__global__ void packt_kernel(const float* __restrict__ src, float4* __restrict__ dst,
                             int O, int K, int dstStride, int dstOff) {
    int idx = blockIdx.x * 256 + threadIdx.x;
    if (idx < O * (K / 4)) {
        int o = idx % O, kk = idx / O;
        const float* s = src + o * K + 4 * kk;
        dst[kk * dstStride + dstOff + o] = make_float4(s[0], s[1], s[2], s[3]);
    }
}

// pre[b][tt][h] = sum_k x[b][T-1-tt][k]*W_ih[h][k] + b_ih[h] + b_hh[h]
// Wiht packed transposed: [kk*400 + h] -> coalesced over lanes=h.
__global__ __launch_bounds__(256) void pre_kernel(
    const float* __restrict__ x, const float4* __restrict__ Wiht,
    const float* __restrict__ b_ih, const float* __restrict__ b_hh,
    float* __restrict__ pre) {
    int b = blockIdx.y;
    int tt0 = blockIdx.x * TCH;
    __shared__ float xs[TCH][DIN];
    int tid = threadIdx.x;
    for (int idx = tid; idx < TCH * DIN; idx += 256) {
        int r = idx / DIN, k = idx % DIN;
        int tsrc = TT - 1 - (tt0 + r);
        xs[r][k] = x[(b * TT + tsrc) * DIN + k];
    }
    __syncthreads();
    for (int h = tid; h < DH; h += 256) {
        float bias = b_ih[h] + b_hh[h];
        float acc[TCH];
        #pragma unroll
        for (int r = 0; r < TCH; ++r) acc[r] = bias;
        for (int kk = 0; kk < DIN / 4; ++kk) {
            float4 w = Wiht[kk * DH + h];
            #pragma unroll
            for (int r = 0; r < TCH; ++r) {
                float4 xv = *(const float4*)(&xs[r][4 * kk]);
                acc[r] = dot4(w, xv, acc[r]);
            }
        }
        for (int r = 0; r < TCH; ++r)
            pre[(size_t)(b * TT + tt0 + r) * DH + h] = acc[r];
    }
}

// Serial scan: h_t = relu(pre_t + W_hh h_{t-1}); writes h_t in-place over pre_t.
__global__ __launch_bounds__(512, 2) void rnn_kernel(
    const float4* __restrict__ Wpk, const float* __restrict__ h0,
    float* __restrict__ hs) {
    extern __shared__ float smem[];
    float4* Wl     = (float4*)smem;                    // [NLDSC][288]
    float* hcur    = smem + NLDSC * NLROWS * 4;        // 400
    float* partial = hcur + DH;                        // 112

    const int b = blockIdx.x, tid = threadIdx.x;
    const bool isRow = (tid < DH);
    const int row = isRow ? tid : tid - DH;
    const int c0  = isRow ? 0 : HELPC0;

    // Register-resident W chunks, pinned so the compiler cannot sink the loads.
    float4 W[NREG];
    #pragma unroll
    for (int c = 0; c < NREG; ++c) {
        float4 w = Wpk[(c0 + c) * DH + row];
        PIN4(w);
        W[c] = w;
    }

    for (int i = tid; i < NLDSC * NLROWS; i += 512) {
        int c = i / NLROWS, r = i % NLROWS;
        Wl[i] = Wpk[(HELPC0 + c) * DH + (RL0 + r)];
    }
    if (isRow) hcur[row] = h0[row];
    __syncthreads();

    float* base = hs + (size_t)b * TT * DH;
    float pre_cur = isRow ? base[row] : 0.f;

    for (int tt = 0; tt < TT; ++tt) {
        float pre_nxt = 0.f;
        if (isRow && tt + 1 < TT) pre_nxt = base[(tt + 1) * DH + row];

        float a0 = 0.f, a1 = 0.f, a2 = 0.f, a3 = 0.f;
        #pragma unroll
        for (int c = 0; c < NREG; c += 4) {
            float4 h4;
            h4 = *(const float4*)(hcur + 4 * (c0 + c));     a0 = dot4(W[c],     h4, a0);
            h4 = *(const float4*)(hcur + 4 * (c0 + c + 1)); a1 = dot4(W[c + 1], h4, a1);
            h4 = *(const float4*)(hcur + 4 * (c0 + c + 2)); a2 = dot4(W[c + 2], h4, a2);
            h4 = *(const float4*)(hcur + 4 * (c0 + c + 3)); a3 = dot4(W[c + 3], h4, a3);
        }
        if (isRow) {
            if (row >= RL0) {
                #pragma unroll
                for (int c = 0; c < NLDSC; ++c) {
                    float4 w  = Wl[c * NLROWS + (row - RL0)];
                    float4 h4 = *(const float4*)(hcur + 4 * (HELPC0 + c));
                    if ((c & 3) == 0)      a0 = dot4(w, h4, a0);
                    else if ((c & 3) == 1) a1 = dot4(w, h4, a1);
                    else if ((c & 3) == 2) a2 = dot4(w, h4, a2);
                    else                   a3 = dot4(w, h4, a3);
                }
                #pragma unroll
                for (int c = 0; c < NSTRC; ++c) {
                    float4 w  = Wpk[(STRC0 + c) * DH + row];
                    float4 h4 = *(const float4*)(hcur + 4 * (STRC0 + c));
                    if ((c & 3) == 0)      a0 = dot4(w, h4, a0);
                    else if ((c & 3) == 1) a1 = dot4(w, h4, a1);
                    else if ((c & 3) == 2) a2 = dot4(w, h4, a2);
                    else                   a3 = dot4(w, h4, a3);
                }
            } else {
                #pragma unroll
                for (int c = 0; c < 4; ++c) {  // chunks 96..99
                    float4 w  = Wpk[(96 + c) * DH + row];
                    float4 h4 = *(const float4*)(hcur + 4 * (96 + c));
                    if (c == 0)      a0 = dot4(w, h4, a0);
                    else if (c == 1) a1 = dot4(w, h4, a1);
                    else if (c == 2) a2 = dot4(w, h4, a2);
                    else             a3 = dot4(w, h4, a3);
                }
            }
        } else {
            partial[row] = (a0 + a1) + (a2 + a3);
        }
        __syncthreads();
        if (isRow) {
            float acc = pre_cur + (a0 + a1) + (a2 + a3);
            if (row < RL0) acc += partial[row];
            float v = fmaxf(acc, 0.f);
            hcur[row] = v;
            base[tt * DH + row] = v;
            pre_cur = pre_nxt;
        }
        __syncthreads();
    }
}

// Fused downstream over (b, 16-t chunk). All weights packed transposed
// (coalesced lane=o), activations broadcast from LDS, 16-row reuse per weight.
__global__ __launch_bounds__(320, 3) void e_kernel(
    const float* __restrict__ hs, const float* __restrict__ eps,
    const float* __restrict__ z0,
    const float4* __restrict__ Wzt,   // [100][160] (part,o)
    const float* __restrict__ b_loc, const float* __restrict__ b_scale,
    const float4* __restrict__ g1t, const float* __restrict__ gb1,   // [20][200]
    const float4* __restrict__ p1t, const float* __restrict__ pb1,
    const float4* __restrict__ g2t, const float* __restrict__ gb2,   // [50][80]
    const float4* __restrict__ p2t, const float* __restrict__ pb2,
    const float4* __restrict__ lWt, const float* __restrict__ lb,    // [20][80]
    const float4* __restrict__ sWt, const float* __restrict__ sb,
    const float4* __restrict__ e1t, const float* __restrict__ eb1,   // [20][100]
    const float4* __restrict__ e2t, const float* __restrict__ eb2,   // [25][100]
    const float4* __restrict__ e3t, const float* __restrict__ eb3,   // [25][88]
    float* __restrict__ out) {
    __shared__ float u1[17 * DH];       // hsr[17][400] | A,P[16][200] | h1,h2[16][100]
    __shared__ float u2[2 * 17 * DZ];   // zpre[2][17][80] | gate,prop[16][80]
    __shared__ float zl[17][DZ];

    float (*hsr)[DH]  = (float(*)[DH])u1;
    float (*A)[DTR]   = (float(*)[DTR])u1;
    float (*P)[DTR]   = (float(*)[DTR])(u1 + 16 * DTR);
    float (*h1)[DE]   = (float(*)[DE])u1;
    float (*h2)[DE]   = (float(*)[DE])(u1 + 16 * DE);
    float (*gate)[DZ] = (float(*)[DZ])u2;
    float (*prop)[DZ] = (float(*)[DZ])(u2 + 16 * DZ);

    int b = blockIdx.y;
    int t0 = blockIdx.x * TCH;
    int tid = threadIdx.x;

    // P0: stage rnn_out rows r=0..16 <-> t=t0-1+r (hs index T-1-t)
    for (int idx = tid; idx < 17 * DH; idx += 320) {
        int r = idx / DH, k = idx % DH;
        int t = t0 - 1 + r;
        hsr[r][k] = (t >= 0) ? hs[((size_t)b * TT + (TT - 1 - t)) * DH + k] : 0.f;
    }
    __syncthreads();

    // P1: z pre-activations. 320 tasks = rh{0,1} x part{loc,scale} x o(80)
    {
        int rh = tid / 160, rem = tid % 160;      // rem = part*80+o
        int rbeg = rh ? 9 : 0, rend = rh ? 17 : 9;
        float bias = (rem < DZ) ? b_loc[rem] : b_scale[rem - DZ];
        float acc[9];
        #pragma unroll
        for (int i = 0; i < 9; ++i) acc[i] = bias;
        for (int kk = 0; kk < DH / 4; ++kk) {
            float4 w = Wzt[kk * 160 + rem];
            #pragma unroll
            for (int i = 0; i < 9; ++i) {
                if (rbeg + i < rend) {
                    float4 hv = *(const float4*)(&hsr[rbeg + i][4 * kk]);
                    acc[i] = dot4(w, hv, acc[i]);
                }
            }
        }
        int part = rem / DZ, o = rem % DZ;
        for (int i = 0; i < 9 && rbeg + i < rend; ++i)
            u2[part * (17 * DZ) + (rbeg + i) * DZ + o] = acc[i];
    }
    __syncthreads();

    // P1b: z = z_loc + softplus(z_scale_pre)*eps (row r=0 at t0=0 -> z0)
    for (int idx = tid; idx < 17 * DZ; idx += 320) {
        int r = idx / DZ, o = idx % DZ;
        int t = t0 - 1 + r;
        float zv;
        if (t < 0) zv = z0[o];
        else {
            float sp = softplusf(u2[17 * DZ + r * DZ + o]);
            zv = u2[r * DZ + o] + sp * eps[((size_t)b * TT + t) * DZ + o];
        }
        zl[r][o] = zv;
    }
    __syncthreads();

    // P2: A=relu(zs@gW1^T+gb1), P=relu(zs@pW1^T+pb1); zs row r -> zl[r]
    for (int task = tid; task < 2 * DTR; task += 320) {
        int rh = task / DTR, o = task % DTR;
        int rbeg = rh * 8;
        float accA[8], accP[8];
        float bg = gb1[o], bp = pb1[o];
        #pragma unroll
        for (int i = 0; i < 8; ++i) { accA[i] = bg; accP[i] = bp; }
        for (int kk = 0; kk < DZ / 4; ++kk) {
            float4 wg = g1t[kk * DTR + o];
            float4 wp = p1t[kk * DTR + o];
            #pragma unroll
            for (int i = 0; i < 8; ++i) {
                float4 zv = *(const float4*)(&zl[rbeg + i][4 * kk]);
                accA[i] = dot4(wg, zv, accA[i]);
                accP[i] = dot4(wp, zv, accP[i]);
            }
        }
        #pragma unroll
        for (int i = 0; i < 8; ++i) {
            A[rbeg + i][o] = fmaxf(accA[i], 0.f);
            P[rbeg + i][o] = fmaxf(accP[i], 0.f);
        }
    }
    __syncthreads();

    // P3: gate = sigmoid(A@gW2^T+gb2); prop = P@pW2^T+pb2. 320 tasks.
    {
        int o = tid % DZ, mr = tid / DZ;
        int mat = mr >> 1, rh = mr & 1, rbeg = rh * 8;
        const float4* Wt = mat ? p2t : g2t;
        float bias = mat ? pb2[o] : gb2[o];
        float acc[8];
        #pragma unroll
        for (int i = 0; i < 8; ++i) acc[i] = bias;
        for (int kk = 0; kk < DTR / 4; ++kk) {
            float4 w = Wt[kk * DZ + o];
            #pragma unroll
            for (int i = 0; i < 8; ++i) {
                const float* src = mat ? &P[rbeg + i][4 * kk] : &A[rbeg + i][4 * kk];
                float4 v = *(const float4*)src;
                acc[i] = dot4(w, v, acc[i]);
            }
        }
        for (int i = 0; i < 8; ++i) {
            if (mat) prop[rbeg + i][o] = acc[i];
            else     gate[rbeg + i][o] = sigmoidf(acc[i]);
        }
    }
    __syncthreads();

    // P4: trans_loc / trans_scale -> out[88..248)
    {
        int o = tid % DZ, wr = tid / DZ;
        int which = wr >> 1, rh = wr & 1, rbeg = rh * 8;
        float acc[8];
        if (which == 0) {
            float bias = lb[o];
            #pragma unroll
            for (int i = 0; i < 8; ++i) acc[i] = bias;
            for (int kk = 0; kk < DZ / 4; ++kk) {
                float4 w = lWt[kk * DZ + o];
                #pragma unroll
                for (int i = 0; i < 8; ++i) {
                    float4 zv = *(const float4*)(&zl[rbeg + i][4 * kk]);
                    acc[i] = dot4(w, zv, acc[i]);
                }
            }
            for (int i = 0; i < 8; ++i) {
                int r = rbeg + i;
                float g = gate[r][o];
                float tl = (1.f - g) * acc[i] + g * prop[r][o];
                out[((size_t)b * TT + t0 + r) * DOUT + DIN + o] = tl;
            }
        } else {
            float bias = sb[o];
            #pragma unroll
            for (int i = 0; i < 8; ++i) acc[i] = bias;
            for (int kk = 0; kk < DZ / 4; ++kk) {
                float4 w = sWt[kk * DZ + o];
                #pragma unroll
                for (int i = 0; i < 8; ++i) {
                    float4 pv = *(const float4*)(&prop[rbeg + i][4 * kk]);
                    pv.x = fmaxf(pv.x, 0.f); pv.y = fmaxf(pv.y, 0.f);
                    pv.z = fmaxf(pv.z, 0.f); pv.w = fmaxf(pv.w, 0.f);
                    acc[i] = dot4(w, pv, acc[i]);
                }
            }
            for (int i = 0; i < 8; ++i)
                out[((size_t)b * TT + t0 + rbeg + i) * DOUT + DIN + DZ + o] = softplusf(acc[i]);
        }
    }
    __syncthreads();

    // P5: h1 = relu(z@eW1^T+eb1); z row for t=t0+r is zl[r+1]
    for (int task = tid; task < 2 * DE; task += 320) {
        int rh = task / DE, o = task % DE, rbeg = rh * 8;
        float acc[8];
        float bias = eb1[o];
        #pragma unroll
        for (int i = 0; i < 8; ++i) acc[i] = bias;
        for (int kk = 0; kk < DZ / 4; ++kk) {
            float4 w = e1t[kk * DE + o];
            #pragma unroll
            for (int i = 0; i < 8; ++i) {
                float4 zv = *(const float4*)(&zl[rbeg + i + 1][4 * kk]);
                acc[i] = dot4(w, zv, acc[i]);
            }
        }
        for (int i = 0; i < 8; ++i) h1[rbeg + i][o] = fmaxf(acc[i], 0.f);
    }
    __syncthreads();

    // P6: h2 = relu(h1@eW2^T+eb2)
    for (int task = tid; task < 2 * DE; task += 320) {
        int rh = task / DE, o = task % DE, rbeg = rh * 8;
        float acc[8];
        float bias = eb2[o];
        #pragma unroll
        for (int i = 0; i < 8; ++i) acc[i] = bias;
        for (int kk = 0; kk < DE / 4; ++kk) {
            float4 w = e2t[kk * DE + o];
            #pragma unroll
            for (int i = 0; i < 8; ++i) {
                float4 hv = *(const float4*)(&h1[rbeg + i][4 * kk]);
                acc[i] = dot4(w, hv, acc[i]);
            }
        }
        for (int i = 0; i < 8; ++i) h2[rbeg + i][o] = fmaxf(acc[i], 0.f);
    }
    __syncthreads();

    // P7: emis = sigmoid(h2@eW3^T+eb3) -> out[0..88)
    for (int task = tid; task < 2 * DIN; task += 320) {
        int rh = task / DIN, o = task % DIN, rbeg = rh * 8;
        float acc[8];
        float bias = eb3[o];
        #pragma unroll
        for (int i = 0; i < 8; ++i) acc[i] = bias;
        for (int kk = 0; kk < DE / 4; ++kk) {
            float4 w = e3t[kk * DIN + o];
            #pragma unroll
            for (int i = 0; i < 8; ++i) {
                float4 hv = *(const float4*)(&h2[rbeg + i][4 * kk]);
                acc[i] = dot4(w, hv, acc[i]);
            }
        }
        for (int i = 0; i < 8; ++i)
            out[((size_t)b * TT + t0 + rbeg + i) * DOUT + o] = sigmoidf(acc[i]);
    }
}

static inline void packt(const float* src, float4* dst, int O, int K,
                         int stride, int off, hipStream_t stream) {
    int total = O * (K / 4);
    packt_kernel<<<(total + 255) / 256, 256, 0, stream>>>(src, dst, O, K, stride, off);
}

extern "C" void kernel_launch(void* const* d_in, const int* in_sizes, int n_in,
                              void* d_out, int out_size, void* d_ws, size_t ws_size,
                              hipStream_t stream) {
    const float* x       = (const float*)d_in[0];
    const float* eps     = (const float*)d_in[1];
    const float* W_ih    = (const float*)d_in[2];
    const float* W_hh    = (const float*)d_in[3];
    const float* b_ih    = (const float*)d_in[4];
    const float* b_hh    = (const float*)d_in[5];
    const float* h0      = (const float*)d_in[6];
    const float* z0      = (const float*)d_in[7];
    const float* W_loc   = (const float*)d_in[8];
    const float* b_loc   = (const float*)d_in[9];
    const float* W_scale = (const float*)d_in[10];
    const float* b_scale = (const float*)d_in[11];
    const float* gW1 = (const float*)d_in[12];
    const float* gb1 = (const float*)d_in[13];
    const float* gW2 = (const float*)d_in[14];
    const float* gb2 = (const float*)d_in[15];
    const float* pW1 = (const float*)d_in[16];
    const float* pb1 = (const float*)d_in[17];
    const float* pW2 = (const float*)d_in[18];
    const float* pb2 = (const float*)d_in[19];
    const float* sW  = (const float*)d_in[20];
    const float* sb  = (const float*)d_in[21];
    const float* lW  = (const float*)d_in[22];
    const float* lb  = (const float*)d_in[23];
    const float* eW1 = (const float*)d_in[24];
    const float* eb1 = (const float*)d_in[25];
    const float* eW2 = (const float*)d_in[26];
    const float* eb2 = (const float*)d_in[27];
    const float* eW3 = (const float*)d_in[28];
    const float* eb3 = (const float*)d_in[29];

    float* wsf = (float*)d_ws;
    float* prebuf = wsf;                                  // B*T*H floats
    float4* pk = (float4*)(wsf + (size_t)BB * TT * DH);   // packed weights
    float4* Wpk  = pk;            // 40000
    float4* Wzt  = pk + 40000;    // 16000 [100][160]
    float4* g1t  = pk + 56000;    // 4000  [20][200]
    float4* p1t  = pk + 60000;    // 4000
    float4* g2t  = pk + 64000;    // 4000  [50][80]
    float4* p2t  = pk + 68000;    // 4000
    float4* lWt  = pk + 72000;    // 1600  [20][80]
    float4* sWt  = pk + 73600;    // 1600
    float4* e1t  = pk + 75200;    // 2000  [20][100]
    float4* e2t  = pk + 77200;    // 2500  [25][100]
    float4* e3t  = pk + 79700;    // 2200  [25][88]
    float4* Wiht = pk + 81900;    // 8800  [22][400]

    packt(W_hh,    Wpk,  DH,  DH,  DH,  0,  stream);
    packt(W_loc,   Wzt,  DZ,  DH,  160, 0,  stream);
    packt(W_scale, Wzt,  DZ,  DH,  160, DZ, stream);
    packt(gW1,     g1t,  DTR, DZ,  DTR, 0,  stream);
    packt(pW1,     p1t,  DTR, DZ,  DTR, 0,  stream);
    packt(gW2,     g2t,  DZ,  DTR, DZ,  0,  stream);
    packt(pW2,     p2t,  DZ,  DTR, DZ,  0,  stream);
    packt(lW,      lWt,  DZ,  DZ,  DZ,  0,  stream);
    packt(sW,      sWt,  DZ,  DZ,  DZ,  0,  stream);
    packt(eW1,     e1t,  DE,  DZ,  DE,  0,  stream);
    packt(eW2,     e2t,  DE,  DE,  DE,  0,  stream);
    packt(eW3,     e3t,  DIN, DE,  DIN, 0,  stream);
    packt(W_ih,    Wiht, DH,  DIN, DH,  0,  stream);

    pre_kernel<<<dim3(TT / TCH, BB), 256, 0, stream>>>(x, Wiht, b_ih, b_hh, prebuf);

    size_t smem = (size_t)NLDSC * NLROWS * sizeof(float4)
                + DH * sizeof(float) + RL0 * sizeof(float);
    hipFuncSetAttribute((const void*)rnn_kernel,
                        hipFuncAttributeMaxDynamicSharedMemorySize, (int)smem);
    rnn_kernel<<<dim3(BB), dim3(512), smem, stream>>>(Wpk, h0, prebuf);

    e_kernel<<<dim3(TT / TCH, BB), 320, 0, stream>>>(
        prebuf, eps, z0, Wzt, b_loc, b_scale,
        g1t, gb1, p1t, pb1, g2t, gb2, p2t, pb2,
        lWt, lb, sWt, sb, e1t, eb1, e2t, eb2, e3t, eb3, (float*)d_out);
}